// Round 13
// baseline (92614.886 us; speedup 1.0000x reference)
//
#include <hip/hip_runtime.h>
#include <cstddef>

using bf16x8 = __attribute__((ext_vector_type(8))) short;
using f32x4  = __attribute__((ext_vector_type(4))) float;

constexpr int Bb = 128;
constexpr int Tt = 256;
constexpr int Hh = 1024;
constexpr int Oo = 64;
constexpr int NBLK = 17;          // 8 h1 + 8 h2 + 1 out, 512 thr each
constexpr int FLAG_STRIDE = 32;   // dwords -> 128B between flags
constexpr int RS = 1032;          // LDS row stride (shorts), +8 pad
constexpr int LDS_BYTES = 64 * RS * 2;   // 132096 B

__device__ __forceinline__ float bf2f(short s) {
  unsigned int u = ((unsigned int)(unsigned short)s) << 16;
  float f;
  __builtin_memcpy(&f, &u, 4);
  return f;
}
__device__ __forceinline__ short f2bf(float f) {
  unsigned int u;
  __builtin_memcpy(&u, &f, 4);
  u += 0x7fffu + ((u >> 16) & 1u);  // round-to-nearest-even
  return (short)(u >> 16);
}
__device__ __forceinline__ bf16x8 as_bf(int4 v) {
  union { int4 i; bf16x8 b; } u; u.i = v; return u.b;
}
__device__ __forceinline__ unsigned ldu(const unsigned* p) {
  return __hip_atomic_load((unsigned*)p, __ATOMIC_RELAXED, __HIP_MEMORY_SCOPE_AGENT);
}

// Agent-scope (sc1) coherent 16B load — bypasses per-XCD L2, LLC-coherent.
#define LD16A(d, p) asm volatile("global_load_dwordx4 %0, %1, off sc1" \
                                 : "=v"(d) : "v"((const void*)(p)))

// Stage a 64-row x 1024-col bf16 slab (global, row stride Hh) into LDS, once
// per block. 512 threads x 16 flat sc1 loads (fully coalesced). This is THE
// fix for r9-r12's bottleneck: sc1 A-bytes/phase drop 33MB -> 4.5MB because
// 8 waves share one staged copy instead of each re-reading global state.
__device__ __forceinline__ void stage64(short* As, const short* src, int tid) {
  const int row = tid >> 3, c8 = tid & 7;
  const short* gp = src + (size_t)row * Hh + c8 * 8;
  short* lp = As + row * RS + c8 * 8;
  int4 r[16];
#pragma unroll
  for (int j = 0; j < 16; ++j) LD16A(r[j], gp + j * 64);
  asm volatile("s_waitcnt vmcnt(0)" ::: "memory");
#pragma unroll
  for (int j = 0; j < 16; ++j) *(int4*)(lp + j * 64) = r[j];
}

// Wave MFMA pass: 16 rows (from LDS) x 128 cols (8 frags), K=1024.
// B from L2-resident weights, 3-deep chunk pipeline (2-chunk lookahead).
__device__ __forceinline__ void lds_pass8(const short* As, int rowoff, int lm, int q,
    const short* __restrict__ Bw, int bstride, int colw, f32x4 (&acc)[8]) {
  const short* ap = As + (rowoff + lm) * RS + q * 8;
  const short* bp = Bw + (size_t)(colw + lm) * bstride + q * 8;
  const size_t fs = (size_t)16 * bstride;
  int4 bv[3][8];
#pragma unroll
  for (int n = 0; n < 8; ++n) bv[0][n] = *(const int4*)(bp + n * fs);
#pragma unroll
  for (int n = 0; n < 8; ++n) bv[1][n] = *(const int4*)(bp + n * fs + 32);
#pragma unroll
  for (int c = 0; c < 32; ++c) {
    if (c + 2 < 32) {
#pragma unroll
      for (int n = 0; n < 8; ++n)
        bv[(c + 2) % 3][n] = *(const int4*)(bp + n * fs + (c + 2) * 32);
    }
    const bf16x8 a = as_bf(*(const int4*)(ap + c * 32));
#pragma unroll
    for (int n = 0; n < 8; ++n)
      acc[n] = __builtin_amdgcn_mfma_f32_16x16x32_bf16(a, as_bf(bv[c % 3][n]), acc[n], 0, 0, 0);
  }
}

// Out role: flat sc1 A (16 rows), 64-col pass (4 frags), 3-deep B pipeline.
__device__ __forceinline__ void load_A32(int4 (&av)[32], const short* A,
                                         int rowb, int lm, int q) {
  const short* ap = A + (size_t)(rowb + lm) * Hh + q * 8;
#pragma unroll
  for (int c = 0; c < 32; ++c) LD16A(av[c], ap + (size_t)c * 32);
  asm volatile("s_waitcnt vmcnt(0)" ::: "memory");
}
__device__ __forceinline__ void flat_pass4(const int4 (&av)[32],
    const short* __restrict__ Bw, int lm, int q, f32x4 (&acc)[4]) {
  const short* bp = Bw + (size_t)lm * Hh + q * 8;
  const size_t fs = (size_t)16 * Hh;
  int4 bv[3][4];
#pragma unroll
  for (int n = 0; n < 4; ++n) bv[0][n] = *(const int4*)(bp + n * fs);
#pragma unroll
  for (int n = 0; n < 4; ++n) bv[1][n] = *(const int4*)(bp + n * fs + 32);
#pragma unroll
  for (int c = 0; c < 32; ++c) {
    if (c + 2 < 32) {
#pragma unroll
      for (int n = 0; n < 4; ++n)
        bv[(c + 2) % 3][n] = *(const int4*)(bp + n * fs + (c + 2) * 32);
    }
    const bf16x8 a = as_bf(av[c]);
#pragma unroll
    for (int n = 0; n < 4; ++n)
      acc[n] = __builtin_amdgcn_mfma_f32_16x16x32_bf16(a, as_bf(bv[c % 3][n]), acc[n], 0, 0, 0);
  }
}

// Hierarchical RMW-free grid barrier (structure identical to rounds 9-12).
__device__ __forceinline__ void grid_barrier(unsigned* flags, unsigned* go,
                                             unsigned gen, int bid, int tid) {
  __builtin_amdgcn_s_waitcnt(0);   // drain this wave's sc1 state stores
  __syncthreads();
  if (tid == 0)
    __hip_atomic_store(flags + (size_t)bid * FLAG_STRIDE, gen,
                       __ATOMIC_RELAXED, __HIP_MEMORY_SCOPE_AGENT);
  if (bid == 0) {
    if (tid < 64) {
      const unsigned* f = flags + (size_t)tid * FLAG_STRIDE;
      for (;;) {
        const unsigned a = ldu(f);
        const unsigned b = ldu(f +  64 * FLAG_STRIDE);
        const unsigned c = ldu(f + 128 * FLAG_STRIDE);
        const unsigned d = ldu(f + 192 * FLAG_STRIDE);
        if (__all((a >= gen) && (b >= gen) && (c >= gen) && (d >= gen))) break;
        __builtin_amdgcn_s_sleep(2);
      }
      if (tid == 0)
        __hip_atomic_store(go, gen, __ATOMIC_RELAXED, __HIP_MEMORY_SCOPE_AGENT);
    }
  } else if (tid < 64) {
    while (ldu(go) < gen)
      __builtin_amdgcn_s_sleep(2);
  }
  __syncthreads();
  asm volatile("" ::: "memory");
}

// pack bf16 pair across lanes (lm, lm^1), store one coherent dword from even lm
#define ST_BF16_PAIR(BASE, ROW, COL, HV) do {                              \
    const int _ov = __shfl_xor((int)(unsigned short)(HV), 1, 64);          \
    if ((lm & 1) == 0) {                                                   \
      const unsigned _pk = (unsigned)(unsigned short)(HV) | ((unsigned)_ov << 16); \
      __hip_atomic_store((unsigned*)((BASE) + (ROW) * Hh + (COL)), _pk,    \
                         __ATOMIC_RELAXED, __HIP_MEMORY_SCOPE_AGENT);      \
    } } while (0)

struct RP {
  short* h1bf;    // ring of 4: h1(t) at slot t&3
  short* h2bf;    // ring of 2: h2(t) at slot t&1
  float* h2f;     // fp32 master of h2, block-local plain RW
  const short* prex;
  const short* whh1; const short* wih2; const short* whh2;
  const short* wg; const short* wo1; const short* wo2;
  const float* b_ih2; const float* b_hh2;
  const float* bg; const float* bo1; const float* bo2;
  float* out;
  unsigned* flags;
  unsigned* go;
};

// Schedule (identical dataflow to r10-r12), 258 phases, 1 barrier each:
//  phase k: h1 blocks compute h1(k-1); h2 blocks compute h2(k-2) (4 passes,
//  3 staged A's); out block computes out(k-3) (both heads).
// Blocks: bid 0-7 h1 (64r x 256c), 8-15 h2 (64r x 256c), 16 out.
// bid%8 = XCD: h1 and h2 blocks with the same bid%8 share a column range,
// keeping each XCD's weight slice ~2.5MB (L2-resident, never invalidated).
__global__ void __launch_bounds__(512, 2) rnn_kernel(RP p) {
  extern __shared__ short As[];
  const int tid = threadIdx.x;
  const int lane = tid & 63;
  const int wv = tid >> 6;          // 0..7
  const int lm = lane & 15;
  const int q = lane >> 4;
  const int bid = blockIdx.x;
  const size_t HS = (size_t)Bb * Hh;

  int role, row_base = 0, col_base = 0;
  if (bid < 8)       { role = 0; row_base = (bid >> 2) * 64; col_base = (bid & 3) * 256; }
  else if (bid < 16) { role = 1; row_base = ((bid - 8) >> 2) * 64; col_base = ((bid - 8) & 3) * 256; }
  else               { role = 2; }

  const int rowoff = 16 * (wv >> 1);            // within the 64-row slab
  const int mb     = row_base + rowoff;         // wave-tile row base (roles 0,1)
  const int colw   = col_base + 128 * (wv & 1); // wave-tile col base (roles 0,1)
  const int mbo    = 16 * wv;                   // out role rows

  float bh2[8], bu[8], b1o[4], b2o[4];
  if (role == 1) {
#pragma unroll
    for (int n = 0; n < 8; ++n) {
      const int c = colw + n * 16 + lm;
      bh2[n] = p.b_ih2[c] + p.b_hh2[c];
      bu[n]  = p.bg[c];
    }
  } else if (role == 2) {
#pragma unroll
    for (int n = 0; n < 4; ++n) {
      const int c = n * 16 + lm;
      b1o[n] = p.bo1[c]; b2o[n] = p.bo2[c];
    }
  }

  for (int k = 1; k <= Tt + 2; ++k) {
    if (role == 0) {
      if (k <= Tt) {
        const int t = k - 1;
        stage64(As, p.h1bf + ((k + 2) & 3) * HS + (size_t)row_base * Hh, tid);  // h1(t-1)
        __syncthreads();
        short prs[8][4];
        const short* pr = p.prex + (size_t)t * HS;
#pragma unroll
        for (int n = 0; n < 8; ++n)
#pragma unroll
          for (int r = 0; r < 4; ++r)
            prs[n][r] = pr[(size_t)(mb + q * 4 + r) * Hh + colw + n * 16 + lm];
        f32x4 acc[8];
#pragma unroll
        for (int n = 0; n < 8; ++n) acc[n] = (f32x4){0.f, 0.f, 0.f, 0.f};
        lds_pass8(As, rowoff, lm, q, p.whh1, Hh, colw, acc);
        short* h1o = p.h1bf + ((k + 3) & 3) * HS;   // slot t&3
#pragma unroll
        for (int n = 0; n < 8; ++n)
#pragma unroll
          for (int r = 0; r < 4; ++r) {
            const int row = mb + q * 4 + r, col = colw + n * 16 + lm;
            const short hv = f2bf(tanhf(acc[n][r] + bf2f(prs[n][r])));
            ST_BF16_PAIR(h1o, row, col, hv);
          }
      }
    } else if (role == 1) {
      if (k >= 2 && k <= Tt + 1) {
        const int t = k - 2;
        stage64(As, p.h1bf + ((k + 2) & 3) * HS + (size_t)row_base * Hh, tid);  // h1(t)
        __syncthreads();
        f32x4 acch[8];
#pragma unroll
        for (int n = 0; n < 8; ++n) acch[n] = (f32x4){bh2[n], bh2[n], bh2[n], bh2[n]};
        lds_pass8(As, rowoff, lm, q, p.wih2, Hh, colw, acch);
        if (t > 0) {
          __syncthreads();  // WAR on As
          stage64(As, p.h2bf + ((k + 1) & 1) * HS + (size_t)row_base * Hh, tid); // h2(t-1)
          __syncthreads();
          lds_pass8(As, rowoff, lm, q, p.whh2, Hh, colw, acch);
          f32x4 accu[8];
#pragma unroll
          for (int n = 0; n < 8; ++n) accu[n] = (f32x4){bu[n], bu[n], bu[n], bu[n]};
          lds_pass8(As, rowoff, lm, q, p.wg + Hh, 2 * Hh, colw, accu);
          __syncthreads();
          stage64(As, p.h1bf + ((k + 1) & 3) * HS + (size_t)row_base * Hh, tid); // h1(t-1)
          __syncthreads();
          lds_pass8(As, rowoff, lm, q, p.wg, 2 * Hh, colw, accu);
          short* h2o = p.h2bf + (k & 1) * HS;       // slot t&1
#pragma unroll
          for (int n = 0; n < 8; ++n)
#pragma unroll
            for (int r = 0; r < 4; ++r) {
              const int row = mb + q * 4 + r, col = colw + n * 16 + lm;
              const int idx = row * Hh + col;
              const float u    = 1.0f / (1.0f + expf(-accu[n][r]));
              const float h2o_ = p.h2f[idx];
              const float nv   = fmaf(u, tanhf(acch[n][r]) - h2o_, h2o_);
              p.h2f[idx] = nv;
              const short hv = f2bf(nv);
              ST_BF16_PAIR(h2o, row, col, hv);
            }
        } else {
          short* h2o = p.h2bf + (k & 1) * HS;
#pragma unroll
          for (int n = 0; n < 8; ++n)
#pragma unroll
            for (int r = 0; r < 4; ++r) {
              const int row = mb + q * 4 + r, col = colw + n * 16 + lm;
              const float nv = tanhf(acch[n][r]);
              p.h2f[row * Hh + col] = nv;
              const short hv = f2bf(nv);
              ST_BF16_PAIR(h2o, row, col, hv);
            }
        }
      }
    } else {
      if (k >= 3) {
        const int t = k - 3;
        int4 av[32];
        f32x4 a1[4], a2[4];
#pragma unroll
        for (int n = 0; n < 4; ++n) {
          a1[n] = (f32x4){b1o[n], b1o[n], b1o[n], b1o[n]};
          a2[n] = (f32x4){b2o[n], b2o[n], b2o[n], b2o[n]};
        }
        load_A32(av, p.h1bf + ((k + 1) & 3) * HS, mbo, lm, q);   // h1(t)
        flat_pass4(av, p.wo1, lm, q, a1);
        load_A32(av, p.h2bf + ((k + 1) & 1) * HS, mbo, lm, q);   // h2(t)
        flat_pass4(av, p.wo2, lm, q, a2);
#pragma unroll
        for (int n = 0; n < 4; ++n)
#pragma unroll
          for (int r = 0; r < 4; ++r) {
            const int row = mbo + q * 4 + r, col = n * 16 + lm;
            p.out[(size_t)row * (Tt * Oo) + (size_t)t * Oo + col] =
                tanhf(a1[n][r]) + tanhf(a2[n][r]);
          }
      }
    }
    if (k < Tt + 2) grid_barrier(p.flags, p.go, (unsigned)k, bid, tid);
  }
}

// pre_x[t][b][j] = x[b,t,:] @ W_ih1[j,:] + b_ih1[j] + b_hh1[j]  (stored bf16)
__global__ void __launch_bounds__(256) prex_kernel(
    const float* __restrict__ x, const float* __restrict__ wih1,
    const float* __restrict__ b_ih1, const float* __restrict__ b_hh1,
    short* __restrict__ prex) {
  const int tid = threadIdx.x;
  const int lane = tid & 63;
  const int wv = tid >> 6;
  const int lm = lane & 15;
  const int q = lane >> 4;
  const int bm = blockIdx.x >> 4;
  const int bn = blockIdx.x & 15;
  const int rowbase = bm * 64;
  const int col = bn * 64 + wv * 16 + lm;

  const f32x4 z4 = {0.f, 0.f, 0.f, 0.f};
  f32x4 acc[4];
#pragma unroll
  for (int mt = 0; mt < 4; ++mt) acc[mt] = z4;

#pragma unroll
  for (int kc = 0; kc < 2; ++kc) {
    const float* bp = wih1 + col * 64 + kc * 32 + q * 8;
    bf16x8 bf;
#pragma unroll
    for (int j = 0; j < 8; ++j) bf[j] = f2bf(bp[j]);
#pragma unroll
    for (int mt = 0; mt < 4; ++mt) {
      const float* ap = x + (size_t)(rowbase + mt * 16 + lm) * 64 + kc * 32 + q * 8;
      bf16x8 af;
#pragma unroll
      for (int j = 0; j < 8; ++j) af[j] = f2bf(ap[j]);
      acc[mt] = __builtin_amdgcn_mfma_f32_16x16x32_bf16(af, bf, acc[mt], 0, 0, 0);
    }
  }
  const float bia = b_ih1[col] + b_hh1[col];
#pragma unroll
  for (int mt = 0; mt < 4; ++mt) {
#pragma unroll
    for (int r = 0; r < 4; ++r) {
      const int row = rowbase + mt * 16 + q * 4 + r;  // row = b*256 + t
      const int b  = row >> 8;
      const int tt = row & 255;
      prex[((size_t)tt * Bb + b) * Hh + col] = f2bf(acc[mt][r] + bia);
    }
  }
}

__global__ void conv_kernel(const float* __restrict__ s, short* __restrict__ d, int n) {
  int i = blockIdx.x * blockDim.x + threadIdx.x;
  const int stride = gridDim.x * blockDim.x;
  for (; i < n; i += stride) d[i] = f2bf(s[i]);
}

__global__ void init_kernel(short* h1bf, short* h2bf, float* h2f,
                            unsigned* flags, unsigned* go) {
  const int i = blockIdx.x * blockDim.x + threadIdx.x;  // exactly 128*1024
  h1bf[3 * Bb * Hh + i] = 0;   // h1(-1) ring slot 3
  h2bf[1 * Bb * Hh + i] = 0;   // h2(-1) ring slot 1
  h2f[i] = 0.f;
  if (i < 256) flags[i * FLAG_STRIDE] = (i < NBLK) ? 0u : 0xFFFFFFFFu;
  if (i == 0) *go = 0u;
}

extern "C" void kernel_launch(void* const* d_in, const int* in_sizes, int n_in,
                              void* d_out, int out_size, void* d_ws, size_t ws_size,
                              hipStream_t stream) {
  (void)in_sizes; (void)n_in; (void)out_size; (void)ws_size;
  const float* x      = (const float*)d_in[0];
  const float* W_ih1  = (const float*)d_in[1];
  const float* b_ih1  = (const float*)d_in[2];
  const float* W_hh1  = (const float*)d_in[3];
  const float* b_hh1  = (const float*)d_in[4];
  const float* W_ih2  = (const float*)d_in[5];
  const float* b_ih2  = (const float*)d_in[6];
  const float* W_hh2  = (const float*)d_in[7];
  const float* b_hh2  = (const float*)d_in[8];
  const float* Wg     = (const float*)d_in[9];
  const float* bg     = (const float*)d_in[10];
  const float* Wo1    = (const float*)d_in[11];
  const float* bo1    = (const float*)d_in[12];
  const float* Wo2    = (const float*)d_in[13];
  const float* bo2    = (const float*)d_in[14];

  char* ws = (char*)d_ws;
  size_t off = 0;
  auto alloc = [&](size_t bytes) -> void* {
    void* ptr = ws + off;
    off += (bytes + 255) & ~(size_t)255;
    return ptr;
  };
  short* whh1 = (short*)alloc((size_t)Hh * Hh * 2);
  short* wih2 = (short*)alloc((size_t)Hh * Hh * 2);
  short* whh2 = (short*)alloc((size_t)Hh * Hh * 2);
  short* wg   = (short*)alloc((size_t)Hh * 2 * Hh * 2);
  short* wo1  = (short*)alloc((size_t)Oo * Hh * 2);
  short* wo2  = (short*)alloc((size_t)Oo * Hh * 2);
  short* prex = (short*)alloc((size_t)Bb * Tt * Hh * 2);
  short* h1bf = (short*)alloc((size_t)4 * Bb * Hh * 2);
  short* h2bf = (short*)alloc((size_t)2 * Bb * Hh * 2);
  float* h2f  = (float*)alloc((size_t)Bb * Hh * 4);
  unsigned* flags = (unsigned*)alloc(256 * FLAG_STRIDE * 4);   // 32 KB
  unsigned* go    = (unsigned*)alloc(256);

  conv_kernel<<<1024, 256, 0, stream>>>(W_hh1, whh1, Hh * Hh);
  conv_kernel<<<1024, 256, 0, stream>>>(W_ih2, wih2, Hh * Hh);
  conv_kernel<<<1024, 256, 0, stream>>>(W_hh2, whh2, Hh * Hh);
  conv_kernel<<<2048, 256, 0, stream>>>(Wg,    wg,   Hh * 2 * Hh);
  conv_kernel<<<256,  256, 0, stream>>>(Wo1,   wo1,  Oo * Hh);
  conv_kernel<<<256,  256, 0, stream>>>(Wo2,   wo2,  Oo * Hh);
  init_kernel<<<512, 256, 0, stream>>>(h1bf, h2bf, h2f, flags, go);
  prex_kernel<<<8192, 256, 0, stream>>>(x, W_ih1, b_ih1, b_hh1, prex);

  RP p;
  p.h1bf = h1bf; p.h2bf = h2bf; p.h2f = h2f;
  p.prex = prex;
  p.whh1 = whh1; p.wih2 = wih2; p.whh2 = whh2;
  p.wg = wg; p.wo1 = wo1; p.wo2 = wo2;
  p.b_ih2 = b_ih2; p.b_hh2 = b_hh2;
  p.bg = bg; p.bo1 = bo1; p.bo2 = bo2;
  p.out = (float*)d_out;
  p.flags = flags;
  p.go = go;

  static bool attr_set = false;
  if (!attr_set) {
    hipFuncSetAttribute((const void*)rnn_kernel,
                        hipFuncAttributeMaxDynamicSharedMemorySize, LDS_BYTES);
    attr_set = true;
  }
  rnn_kernel<<<NBLK, 512, LDS_BYTES, stream>>>(p);
}

// Round 14
// 6272.327 us; speedup vs baseline: 14.7656x; 14.7656x over previous
//
#include <hip/hip_runtime.h>
#include <cstddef>

using bf16x8 = __attribute__((ext_vector_type(8))) short;
using f32x4  = __attribute__((ext_vector_type(4))) float;

constexpr int Bb = 128;
constexpr int Tt = 256;
constexpr int Hh = 1024;
constexpr int Oo = 64;
constexpr int NBLK = 200;         // 64 h1 + 64 acc2 + 64 u + 8 out
constexpr int FLAG_STRIDE = 32;   // dwords -> 128B between flags
constexpr int RS = 1048;          // LDS row stride in shorts: 524 dwords ≡ 12 (mod 32)
                                  // -> b128 lane starts spread over all 8 4-bank groups

__device__ __forceinline__ float bf2f(short s) {
  unsigned int u = ((unsigned int)(unsigned short)s) << 16;
  float f;
  __builtin_memcpy(&f, &u, 4);
  return f;
}
__device__ __forceinline__ short f2bf(float f) {
  unsigned int u;
  __builtin_memcpy(&u, &f, 4);
  u += 0x7fffu + ((u >> 16) & 1u);  // round-to-nearest-even
  return (short)(u >> 16);
}
__device__ __forceinline__ bf16x8 as_bf(int4 v) {
  union { int4 i; bf16x8 b; } u; u.i = v; return u.b;
}
__device__ __forceinline__ float ldf(const float* p) {
  return __hip_atomic_load((float*)p, __ATOMIC_RELAXED, __HIP_MEMORY_SCOPE_AGENT);
}
__device__ __forceinline__ void stf(float* p, float v) {
  __hip_atomic_store(p, v, __ATOMIC_RELAXED, __HIP_MEMORY_SCOPE_AGENT);
}
__device__ __forceinline__ unsigned ldu(const unsigned* p) {
  return __hip_atomic_load((unsigned*)p, __ATOMIC_RELAXED, __HIP_MEMORY_SCOPE_AGENT);
}

// Agent-scope (sc1) coherent 16B load — bypasses per-XCD L2, LLC-coherent.
#define LD16A(d, p) asm volatile("global_load_dwordx4 %0, %1, off sc1" \
                                 : "=v"(d) : "v"((const void*)(p)))

// Stage one 16-row x 1024-col bf16 state slab into LDS: 256 threads x 8 flat
// sc1 loads (whole slab in flight at once -> ~1 LLC latency + stream), then
// LDS writes. 4 waves then SHARE this copy: per-phase sc1 A-traffic drops
// 21 MB -> 6.4 MB vs r9's per-wave reads (the r9-r12 bottleneck).
__device__ __forceinline__ void stage16(short* As, const short* src, int tid) {
  const int row = tid >> 4;          // 0..15
  const int c0  = (tid & 15) * 8;    // shorts
  const short* gp = src + (size_t)row * Hh + c0;
  short* lp = As + row * RS + c0;
  int4 r[8];
#pragma unroll
  for (int j = 0; j < 8; ++j) LD16A(r[j], gp + j * 128);
  asm volatile("s_waitcnt vmcnt(0)" ::: "memory");
#pragma unroll
  for (int j = 0; j < 8; ++j) *(int4*)(lp + j * 128) = r[j];
}

// Wave pass: 16 rows (LDS) x 32 cols (2 frags), K=1024. B from L2-resident
// weights (plain cached), 3-deep pipeline. 64 KB B per wave -> ~1.7us/CU.
__device__ __forceinline__ void lds_pass2(const short* As, int lm, int q,
    const short* __restrict__ Bw, int bstride, int colw, f32x4 (&acc)[2]) {
  const short* ap  = As + lm * RS + q * 8;
  const short* bp0 = Bw + (size_t)(colw + lm) * bstride + q * 8;
  const short* bp1 = bp0 + (size_t)16 * bstride;
  int4 b0v[3], b1v[3];
  b0v[0] = *(const int4*)(bp0);      b1v[0] = *(const int4*)(bp1);
  b0v[1] = *(const int4*)(bp0 + 32); b1v[1] = *(const int4*)(bp1 + 32);
#pragma unroll
  for (int c = 0; c < 32; ++c) {
    if (c + 2 < 32) {
      b0v[(c + 2) % 3] = *(const int4*)(bp0 + (c + 2) * 32);
      b1v[(c + 2) % 3] = *(const int4*)(bp1 + (c + 2) * 32);
    }
    const bf16x8 a = as_bf(*(const int4*)(ap + c * 32));
    acc[0] = __builtin_amdgcn_mfma_f32_16x16x32_bf16(a, as_bf(b0v[c % 3]), acc[0], 0, 0, 0);
    acc[1] = __builtin_amdgcn_mfma_f32_16x16x32_bf16(a, as_bf(b1v[c % 3]), acc[1], 0, 0, 0);
  }
}

// Hierarchical RMW-free grid barrier (identical structure to rounds 9-13).
__device__ __forceinline__ void grid_barrier(unsigned* flags, unsigned* go,
                                             unsigned gen, int bid, int tid) {
  __builtin_amdgcn_s_waitcnt(0);
  __syncthreads();
  if (tid == 0)
    __hip_atomic_store(flags + (size_t)bid * FLAG_STRIDE, gen,
                       __ATOMIC_RELAXED, __HIP_MEMORY_SCOPE_AGENT);
  if (bid == 0) {
    if (tid < 64) {
      const unsigned* f = flags + (size_t)tid * FLAG_STRIDE;
      for (;;) {
        const unsigned a = ldu(f);
        const unsigned b = ldu(f +  64 * FLAG_STRIDE);
        const unsigned c = ldu(f + 128 * FLAG_STRIDE);
        const unsigned d = ldu(f + 192 * FLAG_STRIDE);
        if (__all((a >= gen) && (b >= gen) && (c >= gen) && (d >= gen))) break;
        __builtin_amdgcn_s_sleep(2);
      }
      if (tid == 0)
        __hip_atomic_store(go, gen, __ATOMIC_RELAXED, __HIP_MEMORY_SCOPE_AGENT);
    }
  } else if (tid < 64) {
    while (ldu(go) < gen)
      __builtin_amdgcn_s_sleep(2);
  }
  __syncthreads();
  asm volatile("" ::: "memory");
}

// C/D layout (verified m89/m91): col = lane&15, row = (lane>>4)*4 + reg
#define TL(MB, CW, ACC, ...) do {                                          \
    _Pragma("unroll")                                                      \
    for (int n = 0; n < 2; ++n) {                                          \
      _Pragma("unroll")                                                    \
      for (int r = 0; r < 4; ++r) {                                        \
        const int row = (MB) + q * 4 + r;                                  \
        const int col = (CW) + n * 16 + lm;                                \
        const float z = (ACC)[n][r];                                       \
        __VA_ARGS__;                                                       \
      } } } while (0)

#define ST_BF16_PAIR(BASE, ROW, COL, HV) do {                              \
    const int _ov = __shfl_xor((int)(unsigned short)(HV), 1, 64);          \
    if ((lm & 1) == 0) {                                                   \
      const unsigned _pk = (unsigned)(unsigned short)(HV) | ((unsigned)_ov << 16); \
      __hip_atomic_store((unsigned*)((BASE) + (ROW) * Hh + (COL)), _pk,    \
                         __ATOMIC_RELAXED, __HIP_MEMORY_SCOPE_AGENT);      \
    } } while (0)

#define SET_ACC(ACC, V0, V1) do {                                          \
    (ACC)[0] = (f32x4){(V0), (V0), (V0), (V0)};                            \
    (ACC)[1] = (f32x4){(V1), (V1), (V1), (V1)};                            \
  } while (0)

struct RP {
  short* h1a; short* h1b; short* h2bf;
  float* h2f; float* uf; float* ug1f; float* acc2f; float* o1f;
  const short* prex;
  const short* whh1; const short* wih2; const short* whh2;
  const short* wg; const short* wo1; const short* wo2;
  const float* b_ih2; const float* b_hh2;
  const float* bg; const float* bo1; const float* bo2;
  float* out;
  unsigned* flags;
  unsigned* go;
};

// r9 dataflow, fat-block edition. Block = 256 thr = 4 waves sharing one
// staged 16-row A-slab; each wave covers 32 cols.
//  Phase A: bid 0-63 h1 | 64-127 acc2 | 128-191 u-gate | 192-199 out(t-1)
//  Phase B: bid 0-63 h2 blend | 64-127 ug1 | 192-199 o1 head | others idle
__global__ void __launch_bounds__(256, 1) rnn_kernel(RP p) {
  __shared__ short As[16 * RS];     // 33536 B
  const int tid = threadIdx.x;
  const int lane = tid & 63;
  const int wv = tid >> 6;
  const int lm = lane & 15;
  const int q = lane >> 4;
  const int bid = blockIdx.x;

  int roleA, roleB, g;
  if      (bid < 64)  { roleA = 0; roleB = 4; g = bid; }
  else if (bid < 128) { roleA = 1; roleB = 5; g = bid - 64; }
  else if (bid < 192) { roleA = 2; roleB = 7; g = bid - 128; }
  else                { roleA = 3; roleB = 6; g = bid - 192; }
  const bool small = (roleA == 3);              // out/o1 blocks: 16r x 64c
  const int mb   = small ? g * 16 : (g >> 3) * 16;
  const int colw = small ? wv * 32 : (g & 7) * 128 + wv * 32;
  const bool wact = !small || (wv < 2);         // active waves in pass

  float bA0 = 0.f, bA1 = 0.f, bB0 = 0.f, bB1 = 0.f;
  {
    const int c0 = colw + lm, c1 = colw + 16 + lm;
    if (roleA == 1) { bA0 = p.b_ih2[c0] + p.b_hh2[c0]; bA1 = p.b_ih2[c1] + p.b_hh2[c1]; }
    else if (roleA == 2) { bA0 = p.bg[c0]; bA1 = p.bg[c1]; }
    else if (roleA == 3 && wv < 2) { bA0 = p.bo2[c0]; bA1 = p.bo2[c1]; }
    if (roleB == 6 && wv < 2) { bB0 = p.bo1[c0]; bB1 = p.bo1[c1]; }
  }
  const size_t HS = (size_t)Bb * Hh;

  f32x4 acc[2];
  unsigned gen = 0;
  for (int t = 0; t < Tt; ++t) {
    const short* h1in  = (t & 1) ? p.h1b : p.h1a;
    short*       h1out = (t & 1) ? p.h1a : p.h1b;
    // ---------------- Phase A ----------------
    if (roleA == 0) {
      short prs[2][4];
      const short* pr = p.prex + (size_t)t * HS;
#pragma unroll
      for (int n = 0; n < 2; ++n)
#pragma unroll
        for (int r = 0; r < 4; ++r)
          prs[n][r] = pr[(size_t)(mb + q * 4 + r) * Hh + colw + n * 16 + lm];
      stage16(As, h1in + (size_t)mb * Hh, tid);
      __syncthreads();
      SET_ACC(acc, 0.f, 0.f);
      lds_pass2(As, lm, q, p.whh1, Hh, colw, acc);
      TL(mb, colw, acc, {
        const short hv = f2bf(tanhf(z + bf2f(prs[n][r])));
        ST_BF16_PAIR(h1out, row, col, hv);
      });
    } else if (roleA == 1) {
      stage16(As, p.h2bf + (size_t)mb * Hh, tid);
      __syncthreads();
      SET_ACC(acc, bA0, bA1);
      lds_pass2(As, lm, q, p.whh2, Hh, colw, acc);
      TL(mb, colw, acc, { stf(p.acc2f + row * Hh + col, z); });
    } else if (roleA == 2) {
      if (t > 0) {
        float ex[2][4];
#pragma unroll
        for (int n = 0; n < 2; ++n)
#pragma unroll
          for (int r = 0; r < 4; ++r)
            ex[n][r] = ldf(p.ug1f + (mb + q * 4 + r) * Hh + colw + n * 16 + lm);
        stage16(As, p.h2bf + (size_t)mb * Hh, tid);
        __syncthreads();
        SET_ACC(acc, bA0, bA1);
        lds_pass2(As, lm, q, p.wg + Hh, 2 * Hh, colw, acc);
        TL(mb, colw, acc, {
          const float s = z + ex[n][r];
          stf(p.uf + row * Hh + col, 1.0f / (1.0f + expf(-s)));
        });
      }
    } else {
      if (t > 0) {
        float ex[2][4];
        if (wv < 2) {
#pragma unroll
          for (int n = 0; n < 2; ++n)
#pragma unroll
            for (int r = 0; r < 4; ++r)
              ex[n][r] = ldf(p.o1f + (mb + q * 4 + r) * Oo + colw + n * 16 + lm);
        }
        stage16(As, p.h2bf + (size_t)mb * Hh, tid);
        __syncthreads();
        if (wv < 2) {
          SET_ACC(acc, bA0, bA1);
          lds_pass2(As, lm, q, p.wo2, Hh, colw, acc);
          TL(mb, colw, acc, {
            p.out[(size_t)row * (Tt * Oo) + (size_t)(t - 1) * Oo + col] =
                ex[n][r] + tanhf(z);
          });
        }
      }
    }
    ++gen;
    grid_barrier(p.flags, p.go, gen, bid, tid);
    // ---------------- Phase B ----------------
    if (roleB == 4) {
      float a2[2][4], uu[2][4], h2o[2][4];
#pragma unroll
      for (int n = 0; n < 2; ++n)
#pragma unroll
        for (int r = 0; r < 4; ++r) {
          const int idx = (mb + q * 4 + r) * Hh + colw + n * 16 + lm;
          a2[n][r]  = ldf(p.acc2f + idx);
          uu[n][r]  = ldf(p.uf + idx);
          h2o[n][r] = p.h2f[idx];        // block-local plain RW
        }
      stage16(As, h1out + (size_t)mb * Hh, tid);
      __syncthreads();
      SET_ACC(acc, 0.f, 0.f);
      lds_pass2(As, lm, q, p.wih2, Hh, colw, acc);
      TL(mb, colw, acc, {
        const int idx = row * Hh + col;
        const float hn = tanhf(z + a2[n][r]);
        const float nv = fmaf(uu[n][r], hn - h2o[n][r], h2o[n][r]);
        p.h2f[idx] = nv;
        const short hv = f2bf(nv);
        ST_BF16_PAIR(p.h2bf, row, col, hv);
      });
    } else if (roleB == 5) {
      stage16(As, h1out + (size_t)mb * Hh, tid);
      __syncthreads();
      SET_ACC(acc, 0.f, 0.f);
      lds_pass2(As, lm, q, p.wg, 2 * Hh, colw, acc);
      TL(mb, colw, acc, { stf(p.ug1f + row * Hh + col, z); });
    } else if (roleB == 6) {
      stage16(As, h1out + (size_t)mb * Hh, tid);
      __syncthreads();
      if (wv < 2) {
        SET_ACC(acc, bB0, bB1);
        lds_pass2(As, lm, q, p.wo1, Hh, colw, acc);
        TL(mb, colw, acc, { stf(p.o1f + row * Oo + col, tanhf(z)); });
      }
    }
    ++gen;
    grid_barrier(p.flags, p.go, gen, bid, tid);
  }
  // tail: out rows for t = Tt-1
  if (roleA == 3) {
    float ex[2][4];
    if (wv < 2) {
#pragma unroll
      for (int n = 0; n < 2; ++n)
#pragma unroll
        for (int r = 0; r < 4; ++r)
          ex[n][r] = ldf(p.o1f + (mb + q * 4 + r) * Oo + colw + n * 16 + lm);
    }
    stage16(As, p.h2bf + (size_t)mb * Hh, tid);
    __syncthreads();
    if (wv < 2) {
      SET_ACC(acc, bA0, bA1);
      lds_pass2(As, lm, q, p.wo2, Hh, colw, acc);
      TL(mb, colw, acc, {
        p.out[(size_t)row * (Tt * Oo) + (size_t)(Tt - 1) * Oo + col] =
            ex[n][r] + tanhf(z);
      });
    }
  }
}

// pre_x[t][b][j] = x[b,t,:] @ W_ih1[j,:] + b_ih1[j] + b_hh1[j]  (stored bf16)
__global__ void __launch_bounds__(256) prex_kernel(
    const float* __restrict__ x, const float* __restrict__ wih1,
    const float* __restrict__ b_ih1, const float* __restrict__ b_hh1,
    short* __restrict__ prex) {
  const int tid = threadIdx.x;
  const int lane = tid & 63;
  const int wv = tid >> 6;
  const int lm = lane & 15;
  const int q = lane >> 4;
  const int bm = blockIdx.x >> 4;
  const int bn = blockIdx.x & 15;
  const int rowbase = bm * 64;
  const int col = bn * 64 + wv * 16 + lm;

  const f32x4 z4 = {0.f, 0.f, 0.f, 0.f};
  f32x4 acc[4];
#pragma unroll
  for (int mt = 0; mt < 4; ++mt) acc[mt] = z4;

#pragma unroll
  for (int kc = 0; kc < 2; ++kc) {
    const float* bp = wih1 + col * 64 + kc * 32 + q * 8;
    bf16x8 bf;
#pragma unroll
    for (int j = 0; j < 8; ++j) bf[j] = f2bf(bp[j]);
#pragma unroll
    for (int mt = 0; mt < 4; ++mt) {
      const float* ap = x + (size_t)(rowbase + mt * 16 + lm) * 64 + kc * 32 + q * 8;
      bf16x8 af;
#pragma unroll
      for (int j = 0; j < 8; ++j) af[j] = f2bf(ap[j]);
      acc[mt] = __builtin_amdgcn_mfma_f32_16x16x32_bf16(af, bf, acc[mt], 0, 0, 0);
    }
  }
  const float bia = b_ih1[col] + b_hh1[col];
#pragma unroll
  for (int mt = 0; mt < 4; ++mt) {
#pragma unroll
    for (int r = 0; r < 4; ++r) {
      const int row = rowbase + mt * 16 + q * 4 + r;  // row = b*256 + t
      const int b  = row >> 8;
      const int tt = row & 255;
      prex[((size_t)tt * Bb + b) * Hh + col] = f2bf(acc[mt][r] + bia);
    }
  }
}

__global__ void conv_kernel(const float* __restrict__ s, short* __restrict__ d, int n) {
  int i = blockIdx.x * blockDim.x + threadIdx.x;
  const int stride = gridDim.x * blockDim.x;
  for (; i < n; i += stride) d[i] = f2bf(s[i]);
}

__global__ void init_kernel(short* h1a, short* h1b, short* h2bf, float* h2f,
                            float* uf, unsigned* flags, unsigned* go) {
  const int i = blockIdx.x * blockDim.x + threadIdx.x;  // exactly 128*1024
  h1a[i] = 0; h1b[i] = 0; h2bf[i] = 0; h2f[i] = 0.f; uf[i] = 1.0f;
  if (i < 256) flags[i * FLAG_STRIDE] = (i < NBLK) ? 0u : 0xFFFFFFFFu;
  if (i == 0) *go = 0u;
}

extern "C" void kernel_launch(void* const* d_in, const int* in_sizes, int n_in,
                              void* d_out, int out_size, void* d_ws, size_t ws_size,
                              hipStream_t stream) {
  (void)in_sizes; (void)n_in; (void)out_size; (void)ws_size;
  const float* x      = (const float*)d_in[0];
  const float* W_ih1  = (const float*)d_in[1];
  const float* b_ih1  = (const float*)d_in[2];
  const float* W_hh1  = (const float*)d_in[3];
  const float* b_hh1  = (const float*)d_in[4];
  const float* W_ih2  = (const float*)d_in[5];
  const float* b_ih2  = (const float*)d_in[6];
  const float* W_hh2  = (const float*)d_in[7];
  const float* b_hh2  = (const float*)d_in[8];
  const float* Wg     = (const float*)d_in[9];
  const float* bg     = (const float*)d_in[10];
  const float* Wo1    = (const float*)d_in[11];
  const float* bo1    = (const float*)d_in[12];
  const float* Wo2    = (const float*)d_in[13];
  const float* bo2    = (const float*)d_in[14];

  char* ws = (char*)d_ws;
  size_t off = 0;
  auto alloc = [&](size_t bytes) -> void* {
    void* ptr = ws + off;
    off += (bytes + 255) & ~(size_t)255;
    return ptr;
  };
  short* whh1 = (short*)alloc((size_t)Hh * Hh * 2);
  short* wih2 = (short*)alloc((size_t)Hh * Hh * 2);
  short* whh2 = (short*)alloc((size_t)Hh * Hh * 2);
  short* wg   = (short*)alloc((size_t)Hh * 2 * Hh * 2);
  short* wo1  = (short*)alloc((size_t)Oo * Hh * 2);
  short* wo2  = (short*)alloc((size_t)Oo * Hh * 2);
  short* prex = (short*)alloc((size_t)Bb * Tt * Hh * 2);
  short* h1a  = (short*)alloc((size_t)Bb * Hh * 2);
  short* h1b  = (short*)alloc((size_t)Bb * Hh * 2);
  short* h2bf = (short*)alloc((size_t)Bb * Hh * 2);
  float* h2f  = (float*)alloc((size_t)Bb * Hh * 4);
  float* uf   = (float*)alloc((size_t)Bb * Hh * 4);
  float* ug1f = (float*)alloc((size_t)Bb * Hh * 4);
  float* acc2f= (float*)alloc((size_t)Bb * Hh * 4);
  float* o1f  = (float*)alloc((size_t)Bb * Oo * 4);
  unsigned* flags = (unsigned*)alloc(256 * FLAG_STRIDE * 4);   // 32 KB
  unsigned* go    = (unsigned*)alloc(256);

  conv_kernel<<<1024, 256, 0, stream>>>(W_hh1, whh1, Hh * Hh);
  conv_kernel<<<1024, 256, 0, stream>>>(W_ih2, wih2, Hh * Hh);
  conv_kernel<<<1024, 256, 0, stream>>>(W_hh2, whh2, Hh * Hh);
  conv_kernel<<<2048, 256, 0, stream>>>(Wg,    wg,   Hh * 2 * Hh);
  conv_kernel<<<256,  256, 0, stream>>>(Wo1,   wo1,  Oo * Hh);
  conv_kernel<<<256,  256, 0, stream>>>(Wo2,   wo2,  Oo * Hh);
  init_kernel<<<512, 256, 0, stream>>>(h1a, h1b, h2bf, h2f, uf, flags, go);
  prex_kernel<<<8192, 256, 0, stream>>>(x, W_ih1, b_ih1, b_hh1, prex);

  RP p;
  p.h1a = h1a; p.h1b = h1b; p.h2bf = h2bf;
  p.h2f = h2f; p.uf = uf; p.ug1f = ug1f; p.acc2f = acc2f; p.o1f = o1f;
  p.prex = prex;
  p.whh1 = whh1; p.wih2 = wih2; p.whh2 = whh2;
  p.wg = wg; p.wo1 = wo1; p.wo2 = wo2;
  p.b_ih2 = b_ih2; p.b_hh2 = b_hh2;
  p.bg = bg; p.bo1 = bo1; p.bo2 = bo2;
  p.out = (float*)d_out;
  p.flags = flags;
  p.go = go;

  rnn_kernel<<<NBLK, 256, 0, stream>>>(p);
}